// Round 3
// baseline (837.583 us; speedup 1.0000x reference)
//
#include <hip/hip_runtime.h>
#include <math.h>

namespace {
constexpr int N = 50000;
constexpr int E = 20000;
constexpr int NNZ = 800000;
constexpr int DIN = 128;
constexpr int HD = 256;   // H*DOUT

// workspace layout (float-sized slots)
constexpr size_t OFF_UVT    = 0;                              // [4][128]
constexpr size_t OFF_UET    = 512;                            // [4][128]
constexpr size_t OFF_EV     = 1024;                           // [N][4]
constexpr size_t OFF_EE     = OFF_EV   + (size_t)N * 4;       // [E][4]
constexpr size_t OFF_DEN    = OFF_EE   + (size_t)E * 4;       // [N][4]
constexpr size_t OFF_CNTN   = OFF_DEN  + (size_t)N * 4;       // int [N]
constexpr size_t OFF_CNTE   = OFF_CNTN + (size_t)N;           // int [E]
constexpr size_t OFF_PTRN   = OFF_CNTE + (size_t)E;           // int [N+1]
constexpr size_t OFF_PTRE   = OFF_PTRN + (size_t)(N + 1);     // int [E+1]
constexpr size_t OFF_NODEOFE= OFF_PTRE + (size_t)(E + 1);     // int [NNZ]
constexpr size_t OFF_EDGEOFN= OFF_NODEOFE + (size_t)NNZ;      // int [NNZ]
constexpr size_t OFF_FT_RAW = OFF_EDGEOFN + (size_t)NNZ;
constexpr size_t OFF_FT     = (OFF_FT_RAW + 3) & ~(size_t)3;  // [N][256], 16B aligned
}

// ---- kernel 1: u tables: u[h][k] = sum_d W_p[k, h*64+d] * attn[h,d] ----
__global__ void k_u(const float* __restrict__ Wp, const float* __restrict__ attn_v,
                    const float* __restrict__ attn_e,
                    float* __restrict__ uvT, float* __restrict__ ueT) {
    int t = threadIdx.x;
    for (int task = t; task < 1024; task += 256) {
        int which = task >> 9;            // 0: v-table, 1: e-table
        int hk = task & 511;
        int h = hk >> 7, k = hk & 127;
        const float* attn = which ? attn_e : attn_v;
        float s = 0.f;
        #pragma unroll 8
        for (int d = 0; d < 64; ++d)
            s += Wp[k * HD + h * 64 + d] * attn[h * 64 + d];
        (which ? ueT : uvT)[h * 128 + k] = s;
    }
}

// ---- kernel 2: e_v[n,h] = vfeat[n,:] . u_v[h,:];  e_e likewise (one wave/row)
__global__ void k_ev(const float* __restrict__ vfeat, const float* __restrict__ efeat,
                     const float* __restrict__ uvT, const float* __restrict__ ueT,
                     float* __restrict__ e_v, float* __restrict__ e_e) {
    __shared__ float su[2][4][128];
    int t = threadIdx.x;
    for (int idx = t; idx < 512; idx += 256) {
        su[0][0][idx] = uvT[idx];
        su[1][0][idx] = ueT[idx];
    }
    __syncthreads();
    int wave = t >> 6, lane = t & 63;
    int row = blockIdx.x * 4 + wave;
    if (row >= N + E) return;
    const float* feat; const float (*u)[128]; float* out; int r;
    if (row < N) { feat = vfeat; u = su[0]; out = e_v; r = row; }
    else         { feat = efeat; u = su[1]; out = e_e; r = row - N; }
    float f0 = feat[(size_t)r * DIN + lane];
    float f1 = feat[(size_t)r * DIN + 64 + lane];
    float p0 = f0 * u[0][lane] + f1 * u[0][64 + lane];
    float p1 = f0 * u[1][lane] + f1 * u[1][64 + lane];
    float p2 = f0 * u[2][lane] + f1 * u[2][64 + lane];
    float p3 = f0 * u[3][lane] + f1 * u[3][64 + lane];
    #pragma unroll
    for (int off = 32; off > 0; off >>= 1) {
        p0 += __shfl_xor(p0, off, 64);
        p1 += __shfl_xor(p1, off, 64);
        p2 += __shfl_xor(p2, off, 64);
        p3 += __shfl_xor(p3, off, 64);
    }
    if (lane == 0)
        *reinterpret_cast<float4*>(&out[(size_t)r * 4]) = make_float4(p0, p1, p2, p3);
}

// ---- kernel 3: ft = (vfeat @ W_v) * DV2, [N][256]; 64x64 tile SGEMM ----
__global__ __launch_bounds__(256) void k_ft(const float* __restrict__ vfeat,
                                            const float* __restrict__ Wv,
                                            const float* __restrict__ DV2,
                                            float* __restrict__ ft) {
    __shared__ float As[32][65];
    __shared__ float Bs[32][64];
    int tid = threadIdx.x;
    int rowBase = blockIdx.x * 64;
    int colBase = blockIdx.y * 64;
    int tx = tid & 15, ty = tid >> 4;
    int tx4 = tx * 4, ty4 = ty * 4;
    float acc[4][4] = {};
    for (int k0 = 0; k0 < DIN; k0 += 32) {
        #pragma unroll
        for (int i = 0; i < 2; ++i) {
            int e = tid + i * 256;        // 0..511
            int r = e >> 3;               // 0..63
            int k4 = e & 7;               // 0..7
            int row = rowBase + r;
            float4 v = make_float4(0.f, 0.f, 0.f, 0.f);
            if (row < N)
                v = *reinterpret_cast<const float4*>(&vfeat[(size_t)row * DIN + k0 + k4 * 4]);
            As[k4 * 4 + 0][r] = v.x;
            As[k4 * 4 + 1][r] = v.y;
            As[k4 * 4 + 2][r] = v.z;
            As[k4 * 4 + 3][r] = v.w;
        }
        #pragma unroll
        for (int i = 0; i < 2; ++i) {
            int e = tid + i * 256;
            int k = e >> 4;               // 0..31
            int c4 = e & 15;              // 0..15
            *reinterpret_cast<float4*>(&Bs[k][c4 * 4]) =
                *reinterpret_cast<const float4*>(&Wv[(size_t)(k0 + k) * HD + colBase + c4 * 4]);
        }
        __syncthreads();
        #pragma unroll 8
        for (int k = 0; k < 32; ++k) {
            float a0 = As[k][ty4 + 0], a1 = As[k][ty4 + 1];
            float a2 = As[k][ty4 + 2], a3 = As[k][ty4 + 3];
            float4 b = *reinterpret_cast<const float4*>(&Bs[k][tx4]);
            acc[0][0] += a0 * b.x; acc[0][1] += a0 * b.y; acc[0][2] += a0 * b.z; acc[0][3] += a0 * b.w;
            acc[1][0] += a1 * b.x; acc[1][1] += a1 * b.y; acc[1][2] += a1 * b.z; acc[1][3] += a1 * b.w;
            acc[2][0] += a2 * b.x; acc[2][1] += a2 * b.y; acc[2][2] += a2 * b.z; acc[2][3] += a2 * b.w;
            acc[3][0] += a3 * b.x; acc[3][1] += a3 * b.y; acc[3][2] += a3 * b.z; acc[3][3] += a3 * b.w;
        }
        __syncthreads();
    }
    #pragma unroll
    for (int mi = 0; mi < 4; ++mi) {
        int row = rowBase + ty4 + mi;
        if (row < N) {
            float dv = DV2[row];
            float4 o = make_float4(acc[mi][0] * dv, acc[mi][1] * dv,
                                   acc[mi][2] * dv, acc[mi][3] * dv);
            *reinterpret_cast<float4*>(&ft[(size_t)row * HD + colBase + tx4]) = o;
        }
    }
}

// ---- kernel 3b: in-place per-row transpose ft[n][h*64+d] -> ftT[n][d*4+h] ----
__global__ void k_ftT(float* __restrict__ ft) {
    int n = blockIdx.x * 4 + (threadIdx.x >> 6);
    int lane = threadIdx.x & 63;
    if (n >= N) return;
    float* row = &ft[(size_t)n * HD];
    float f0 = row[lane];
    float f1 = row[64 + lane];
    float f2 = row[128 + lane];
    float f3 = row[192 + lane];
    *reinterpret_cast<float4*>(&row[lane * 4]) = make_float4(f0, f1, f2, f3);
}

// ---- kernel 4: histograms (node & edge) + den atomics ----
__global__ void k_histden(const int* __restrict__ node_idx, const int* __restrict__ edge_idx,
                          const float* __restrict__ e_v, const float* __restrict__ e_e,
                          int* __restrict__ cntN, int* __restrict__ cntE,
                          float* __restrict__ den) {
    int i = blockIdx.x * 256 + threadIdx.x;
    if (i >= NNZ) return;
    int n = node_idx[i], e = edge_idx[i];
    atomicAdd(&cntN[n], 1);
    atomicAdd(&cntE[e], 1);
    float4 av = *reinterpret_cast<const float4*>(&e_v[(size_t)n * 4]);
    float4 ae = *reinterpret_cast<const float4*>(&e_e[(size_t)e * 4]);
    atomicAdd(&den[(size_t)n * 4 + 0], __expf(fmaxf(av.x + ae.x, 0.f)));
    atomicAdd(&den[(size_t)n * 4 + 1], __expf(fmaxf(av.y + ae.y, 0.f)));
    atomicAdd(&den[(size_t)n * 4 + 2], __expf(fmaxf(av.z + ae.z, 0.f)));
    atomicAdd(&den[(size_t)n * 4 + 3], __expf(fmaxf(av.w + ae.w, 0.f)));
}

// ---- scan: single block; cnt becomes the scatter cursor (= exclusive prefix) ----
__global__ __launch_bounds__(1024) void k_scan(int* __restrict__ cnt,
                                               int* __restrict__ ptr, int count) {
    __shared__ int part[1024];
    int t = threadIdx.x;
    int C = (count + 1023) / 1024;
    int lo = t * C, hi = min(lo + C, count);
    int s = 0;
    for (int i = lo; i < hi; ++i) s += cnt[i];
    part[t] = s;
    __syncthreads();
    for (int off = 1; off < 1024; off <<= 1) {
        int v = part[t];
        int add = (t >= off) ? part[t - off] : 0;
        __syncthreads();
        part[t] = v + add;
        __syncthreads();
    }
    int run = (t == 0) ? 0 : part[t - 1];
    for (int i = lo; i < hi; ++i) {
        int cv = cnt[i];
        ptr[i] = run;
        cnt[i] = run;
        run += cv;
    }
    if (t == 0) ptr[count] = part[1023];
}

// ---- scatter both CSR payloads: nodeOfE (sorted by edge), edgeOfN (sorted by node)
__global__ void k_scatter2(const int* __restrict__ node_idx, const int* __restrict__ edge_idx,
                           int* __restrict__ cursorN, int* __restrict__ cursorE,
                           int* __restrict__ edgeOfN, int* __restrict__ nodeOfE) {
    int i = blockIdx.x * 256 + threadIdx.x;
    if (i >= NNZ) return;
    int n = node_idx[i], e = edge_idx[i];
    int posN = atomicAdd(&cursorN[n], 1);
    edgeOfN[posN] = e;
    int posE = atomicAdd(&cursorE[e], 1);
    nodeOfE[posE] = n;
}

// ---- kernel 5 (stage 1, EDGE-major, no atomics): one wave per edge ----
// eout[e,d] = 0.25 * sum_{i in edge e} sum_h a[i,h] * ftT[n_i][d][h]
__global__ __launch_bounds__(256) void k_stage1(
        const int* __restrict__ ptrE, const int* __restrict__ nodeOfE,
        const float* __restrict__ e_v, const float* __restrict__ e_e,
        const float* __restrict__ den, const float* __restrict__ ftT,
        float* __restrict__ eout) {
    int e = blockIdx.x * 4 + (threadIdx.x >> 6);
    int lane = threadIdx.x & 63;
    if (e >= E) return;
    int base = ptrE[e];
    int deg = ptrE[e + 1] - base;
    float4 ae = *reinterpret_cast<const float4*>(&e_e[(size_t)e * 4]);
    float acc = 0.f;
    for (int j = 0; j < deg; ++j) {
        int n = nodeOfE[base + j];
        float4 av = *reinterpret_cast<const float4*>(&e_v[(size_t)n * 4]);
        float4 dn = *reinterpret_cast<const float4*>(&den[(size_t)n * 4]);
        float4 f  = *reinterpret_cast<const float4*>(&ftT[(size_t)n * HD + lane * 4]);
        float a0 = __expf(fmaxf(av.x + ae.x, 0.f)) * __builtin_amdgcn_rcpf(dn.x);
        float a1 = __expf(fmaxf(av.y + ae.y, 0.f)) * __builtin_amdgcn_rcpf(dn.y);
        float a2 = __expf(fmaxf(av.z + ae.z, 0.f)) * __builtin_amdgcn_rcpf(dn.z);
        float a3 = __expf(fmaxf(av.w + ae.w, 0.f)) * __builtin_amdgcn_rcpf(dn.w);
        acc += a0 * f.x + a1 * f.y + a2 * f.z + a3 * f.w;
    }
    eout[(size_t)e * 64 + lane] = acc * 0.25f;
}

// ---- kernel 6 (stage 2, NODE-major, no atomics): one wave per node ----
// vout[n,d] = sum_{i in node n} coef_i * eout[e_i, d]
// coef_i = 0.25 * (sum_h a[i,h]) * invDE[e] * DV2[n]
__global__ __launch_bounds__(256) void k_stage2(
        const int* __restrict__ ptrN, const int* __restrict__ edgeOfN,
        const float* __restrict__ e_v, const float* __restrict__ e_e,
        const float* __restrict__ den, const float* __restrict__ invDE,
        const float* __restrict__ DV2,
        const float* __restrict__ eout, float* __restrict__ vout) {
    int n = blockIdx.x * 4 + (threadIdx.x >> 6);
    int lane = threadIdx.x & 63;
    if (n >= N) return;
    int base = ptrN[n];
    int deg = ptrN[n + 1] - base;
    float acc = 0.f;
    if (deg > 0) {
        float4 av = *reinterpret_cast<const float4*>(&e_v[(size_t)n * 4]);
        float4 dn = *reinterpret_cast<const float4*>(&den[(size_t)n * 4]);
        float r0 = __builtin_amdgcn_rcpf(dn.x);
        float r1 = __builtin_amdgcn_rcpf(dn.y);
        float r2 = __builtin_amdgcn_rcpf(dn.z);
        float r3 = __builtin_amdgcn_rcpf(dn.w);
        float dv = 0.25f * DV2[n];
        for (int j = 0; j < deg; ++j) {
            int e = edgeOfN[base + j];
            float4 ae = *reinterpret_cast<const float4*>(&e_e[(size_t)e * 4]);
            float suma = __expf(fmaxf(av.x + ae.x, 0.f)) * r0
                       + __expf(fmaxf(av.y + ae.y, 0.f)) * r1
                       + __expf(fmaxf(av.z + ae.z, 0.f)) * r2
                       + __expf(fmaxf(av.w + ae.w, 0.f)) * r3;
            float cf = suma * invDE[e] * dv;
            acc += cf * eout[(size_t)e * 64 + lane];
        }
    }
    vout[(size_t)n * 64 + lane] = acc;
}

extern "C" void kernel_launch(void* const* d_in, const int* in_sizes, int n_in,
                              void* d_out, int out_size, void* d_ws, size_t ws_size,
                              hipStream_t stream) {
    const float* vfeat   = (const float*)d_in[0];
    const float* efeat   = (const float*)d_in[1];
    const float* DV2     = (const float*)d_in[2];
    const float* invDE   = (const float*)d_in[3];
    const float* Wp      = (const float*)d_in[4];
    const float* Wv      = (const float*)d_in[5];
    const float* attn_v  = (const float*)d_in[6];
    const float* attn_e  = (const float*)d_in[7];
    const int* node_idx  = (const int*)d_in[8];
    const int* edge_idx  = (const int*)d_in[9];

    float* out  = (float*)d_out;
    float* vout = out;                       // [N][64]
    float* eout = out + (size_t)N * 64;      // [E][64]

    float* ws    = (float*)d_ws;
    float* uvT   = ws + OFF_UVT;
    float* ueT   = ws + OFF_UET;
    float* e_v   = ws + OFF_EV;
    float* e_e   = ws + OFF_EE;
    float* den   = ws + OFF_DEN;
    int*   cntN  = (int*)(ws + OFF_CNTN);
    int*   cntE  = (int*)(ws + OFF_CNTE);
    int*   ptrN  = (int*)(ws + OFF_PTRN);
    int*   ptrE  = (int*)(ws + OFF_PTRE);
    int*   nodeOfE = (int*)(ws + OFF_NODEOFE);
    int*   edgeOfN = (int*)(ws + OFF_EDGEOFN);
    float* ft    = ws + OFF_FT;

    // zero den + cntN + cntE (contiguous region)
    hipMemsetAsync(den, 0, (size_t)(N * 4 + N + E) * sizeof(float), stream);

    k_u<<<1, 256, 0, stream>>>(Wp, attn_v, attn_e, uvT, ueT);
    k_ev<<<(N + E + 3) / 4, 256, 0, stream>>>(vfeat, efeat, uvT, ueT, e_v, e_e);
    k_ft<<<dim3((N + 63) / 64, HD / 64), 256, 0, stream>>>(vfeat, Wv, DV2, ft);
    k_ftT<<<(N + 3) / 4, 256, 0, stream>>>(ft);
    k_histden<<<(NNZ + 255) / 256, 256, 0, stream>>>(node_idx, edge_idx, e_v, e_e,
                                                     cntN, cntE, den);
    k_scan<<<1, 1024, 0, stream>>>(cntN, ptrN, N);
    k_scan<<<1, 1024, 0, stream>>>(cntE, ptrE, E);
    k_scatter2<<<(NNZ + 255) / 256, 256, 0, stream>>>(node_idx, edge_idx,
                                                      cntN, cntE, edgeOfN, nodeOfE);
    k_stage1<<<(E + 3) / 4, 256, 0, stream>>>(ptrE, nodeOfE, e_v, e_e, den, ft, eout);
    k_stage2<<<(N + 3) / 4, 256, 0, stream>>>(ptrN, edgeOfN, e_v, e_e, den,
                                              invDE, DV2, eout, vout);
}

// Round 4
// 678.121 us; speedup vs baseline: 1.2352x; 1.2352x over previous
//
#include <hip/hip_runtime.h>
#include <math.h>

namespace {
constexpr int N = 50000;
constexpr int E = 20000;
constexpr int NNZ = 800000;
constexpr int DIN = 128;
constexpr int HD = 256;   // H*DOUT

// workspace layout (float-sized slots)
constexpr size_t OFF_UVT  = 0;                               // [4][128]
constexpr size_t OFF_UET  = 512;                             // [4][128]
constexpr size_t OFF_EV   = 1024;                            // [N][4]
constexpr size_t OFF_EE   = OFF_EV   + (size_t)N * 4;        // [E][4]
constexpr size_t OFF_RDEN = OFF_EE   + (size_t)E * 4;        // [N][4]  (1/den)
constexpr size_t OFF_CNTN = OFF_RDEN + (size_t)N * 4;        // int [N]
constexpr size_t OFF_CNTE = OFF_CNTN + (size_t)N;            // int [E]
constexpr size_t OFF_PTRN = OFF_CNTE + (size_t)E;            // int [N+1]
constexpr size_t OFF_PTRE = OFF_PTRN + (size_t)(N + 2);      // int [E+1] (even base)
constexpr size_t OFF_NOE2 = OFF_PTRE + (size_t)(E + 3);      // int2 [NNZ] {node, inc}
constexpr size_t OFF_EON2 = OFF_NOE2 + (size_t)NNZ * 2;      // int2 [NNZ] {edge, inc}
constexpr size_t OFF_COEF = OFF_EON2 + (size_t)NNZ * 2;      // float [NNZ]
constexpr size_t OFF_FTBF = OFF_COEF + (size_t)NNZ;          // ushort4 [N][64]  (bf16 ftT)

__device__ __forceinline__ unsigned short f2bf(float x) {
    unsigned int u = __float_as_uint(x);
    return (unsigned short)((u + 0x7FFFu + ((u >> 16) & 1u)) >> 16);
}
__device__ __forceinline__ float bf2f(unsigned short b) {
    return __uint_as_float(((unsigned int)b) << 16);
}
}

// ---- kernel 1: u tables: u[h][k] = sum_d W_p[k, h*64+d] * attn[h,d] ----
__global__ void k_u(const float* __restrict__ Wp, const float* __restrict__ attn_v,
                    const float* __restrict__ attn_e,
                    float* __restrict__ uvT, float* __restrict__ ueT) {
    int t = threadIdx.x;
    for (int task = t; task < 1024; task += 256) {
        int which = task >> 9;
        int hk = task & 511;
        int h = hk >> 7, k = hk & 127;
        const float* attn = which ? attn_e : attn_v;
        float s = 0.f;
        #pragma unroll 8
        for (int d = 0; d < 64; ++d)
            s += Wp[k * HD + h * 64 + d] * attn[h * 64 + d];
        (which ? ueT : uvT)[h * 128 + k] = s;
    }
}

// ---- kernel 2: e_v[n,h] = vfeat[n,:] . u_v[h,:];  e_e likewise (one wave/row)
__global__ void k_ev(const float* __restrict__ vfeat, const float* __restrict__ efeat,
                     const float* __restrict__ uvT, const float* __restrict__ ueT,
                     float* __restrict__ e_v, float* __restrict__ e_e) {
    __shared__ float su[2][4][128];
    int t = threadIdx.x;
    for (int idx = t; idx < 512; idx += 256) {
        su[0][0][idx] = uvT[idx];
        su[1][0][idx] = ueT[idx];
    }
    __syncthreads();
    int wave = t >> 6, lane = t & 63;
    int row = blockIdx.x * 4 + wave;
    if (row >= N + E) return;
    const float* feat; const float (*u)[128]; float* out; int r;
    if (row < N) { feat = vfeat; u = su[0]; out = e_v; r = row; }
    else         { feat = efeat; u = su[1]; out = e_e; r = row - N; }
    float f0 = feat[(size_t)r * DIN + lane];
    float f1 = feat[(size_t)r * DIN + 64 + lane];
    float p0 = f0 * u[0][lane] + f1 * u[0][64 + lane];
    float p1 = f0 * u[1][lane] + f1 * u[1][64 + lane];
    float p2 = f0 * u[2][lane] + f1 * u[2][64 + lane];
    float p3 = f0 * u[3][lane] + f1 * u[3][64 + lane];
    #pragma unroll
    for (int off = 32; off > 0; off >>= 1) {
        p0 += __shfl_xor(p0, off, 64);
        p1 += __shfl_xor(p1, off, 64);
        p2 += __shfl_xor(p2, off, 64);
        p3 += __shfl_xor(p3, off, 64);
    }
    if (lane == 0)
        *reinterpret_cast<float4*>(&out[(size_t)r * 4]) = make_float4(p0, p1, p2, p3);
}

// ---- kernel 3: ft = (vfeat @ W_v) * DV2, [N][256]; 64x64 tile SGEMM ----
__global__ __launch_bounds__(256) void k_ft(const float* __restrict__ vfeat,
                                            const float* __restrict__ Wv,
                                            const float* __restrict__ DV2,
                                            float* __restrict__ ft) {
    __shared__ float As[32][65];
    __shared__ float Bs[32][64];
    int tid = threadIdx.x;
    int rowBase = blockIdx.x * 64;
    int colBase = blockIdx.y * 64;
    int tx = tid & 15, ty = tid >> 4;
    int tx4 = tx * 4, ty4 = ty * 4;
    float acc[4][4] = {};
    for (int k0 = 0; k0 < DIN; k0 += 32) {
        #pragma unroll
        for (int i = 0; i < 2; ++i) {
            int e = tid + i * 256;
            int r = e >> 3;
            int k4 = e & 7;
            int row = rowBase + r;
            float4 v = make_float4(0.f, 0.f, 0.f, 0.f);
            if (row < N)
                v = *reinterpret_cast<const float4*>(&vfeat[(size_t)row * DIN + k0 + k4 * 4]);
            As[k4 * 4 + 0][r] = v.x;
            As[k4 * 4 + 1][r] = v.y;
            As[k4 * 4 + 2][r] = v.z;
            As[k4 * 4 + 3][r] = v.w;
        }
        #pragma unroll
        for (int i = 0; i < 2; ++i) {
            int e = tid + i * 256;
            int k = e >> 4;
            int c4 = e & 15;
            *reinterpret_cast<float4*>(&Bs[k][c4 * 4]) =
                *reinterpret_cast<const float4*>(&Wv[(size_t)(k0 + k) * HD + colBase + c4 * 4]);
        }
        __syncthreads();
        #pragma unroll 8
        for (int k = 0; k < 32; ++k) {
            float a0 = As[k][ty4 + 0], a1 = As[k][ty4 + 1];
            float a2 = As[k][ty4 + 2], a3 = As[k][ty4 + 3];
            float4 b = *reinterpret_cast<const float4*>(&Bs[k][tx4]);
            acc[0][0] += a0 * b.x; acc[0][1] += a0 * b.y; acc[0][2] += a0 * b.z; acc[0][3] += a0 * b.w;
            acc[1][0] += a1 * b.x; acc[1][1] += a1 * b.y; acc[1][2] += a1 * b.z; acc[1][3] += a1 * b.w;
            acc[2][0] += a2 * b.x; acc[2][1] += a2 * b.y; acc[2][2] += a2 * b.z; acc[2][3] += a2 * b.w;
            acc[3][0] += a3 * b.x; acc[3][1] += a3 * b.y; acc[3][2] += a3 * b.z; acc[3][3] += a3 * b.w;
        }
        __syncthreads();
    }
    #pragma unroll
    for (int mi = 0; mi < 4; ++mi) {
        int row = rowBase + ty4 + mi;
        if (row < N) {
            float dv = DV2[row];
            float4 o = make_float4(acc[mi][0] * dv, acc[mi][1] * dv,
                                   acc[mi][2] * dv, acc[mi][3] * dv);
            *reinterpret_cast<float4*>(&ft[(size_t)row * HD + colBase + tx4]) = o;
        }
    }
}

// ---- kernel 3b: ft[n][h*64+d] -> packed bf16 ftbf[n][d] = {h0,h1,h2,h3} ----
__global__ void k_ftT(const float* __restrict__ ft, ushort4* __restrict__ ftbf) {
    int n = blockIdx.x * 4 + (threadIdx.x >> 6);
    int lane = threadIdx.x & 63;
    if (n >= N) return;
    const float* row = &ft[(size_t)n * HD];
    ushort4 q;
    q.x = f2bf(row[lane]);
    q.y = f2bf(row[64 + lane]);
    q.z = f2bf(row[128 + lane]);
    q.w = f2bf(row[192 + lane]);
    ftbf[(size_t)n * 64 + lane] = q;
}

// ---- kernel 4: int histograms only ----
__global__ void k_hist(const int* __restrict__ node_idx, const int* __restrict__ edge_idx,
                       int* __restrict__ cntN, int* __restrict__ cntE) {
    int i = blockIdx.x * 256 + threadIdx.x;
    if (i >= NNZ) return;
    atomicAdd(&cntN[node_idx[i]], 1);
    atomicAdd(&cntE[edge_idx[i]], 1);
}

// ---- scan: single block; cnt becomes the scatter cursor (= exclusive prefix) ----
__global__ __launch_bounds__(1024) void k_scan(int* __restrict__ cnt,
                                               int* __restrict__ ptr, int count) {
    __shared__ int part[1024];
    int t = threadIdx.x;
    int C = (count + 1023) / 1024;
    int lo = t * C, hi = min(lo + C, count);
    int s = 0;
    for (int i = lo; i < hi; ++i) s += cnt[i];
    part[t] = s;
    __syncthreads();
    for (int off = 1; off < 1024; off <<= 1) {
        int v = part[t];
        int add = (t >= off) ? part[t - off] : 0;
        __syncthreads();
        part[t] = v + add;
        __syncthreads();
    }
    int run = (t == 0) ? 0 : part[t - 1];
    for (int i = lo; i < hi; ++i) {
        int cv = cnt[i];
        ptr[i] = run;
        cnt[i] = run;
        run += cv;
    }
    if (t == 0) ptr[count] = part[1023];
}

// ---- scatter both CSR payloads with incidence ids ----
__global__ void k_scatter2(const int* __restrict__ node_idx, const int* __restrict__ edge_idx,
                           int* __restrict__ cursorN, int* __restrict__ cursorE,
                           int2* __restrict__ edgeOfN, int2* __restrict__ nodeOfE) {
    int i = blockIdx.x * 256 + threadIdx.x;
    if (i >= NNZ) return;
    int n = node_idx[i], e = edge_idx[i];
    int posN = atomicAdd(&cursorN[n], 1);
    edgeOfN[posN] = make_int2(e, i);
    int posE = atomicAdd(&cursorE[e], 1);
    nodeOfE[posE] = make_int2(n, i);
}

// ---- kernel 5: rden[n] = 1 / sum_{e in n} exp(relu(e_v[n]+e_e[e])), node-major ----
__global__ __launch_bounds__(256) void k_den(
        const int* __restrict__ ptrN, const int2* __restrict__ edgeOfN,
        const float* __restrict__ e_v, const float* __restrict__ e_e,
        float* __restrict__ rden) {
    int n = blockIdx.x * 4 + (threadIdx.x >> 6);
    int lane = threadIdx.x & 63;
    if (n >= N) return;
    int base = ptrN[n];
    int deg = ptrN[n + 1] - base;
    float4 av = *reinterpret_cast<const float4*>(&e_v[(size_t)n * 4]);
    float d0 = 0.f, d1 = 0.f, d2 = 0.f, d3 = 0.f;
    for (int j = lane; j < deg; j += 64) {
        int e = edgeOfN[base + j].x;
        float4 ae = *reinterpret_cast<const float4*>(&e_e[(size_t)e * 4]);
        d0 += __expf(fmaxf(av.x + ae.x, 0.f));
        d1 += __expf(fmaxf(av.y + ae.y, 0.f));
        d2 += __expf(fmaxf(av.z + ae.z, 0.f));
        d3 += __expf(fmaxf(av.w + ae.w, 0.f));
    }
    #pragma unroll
    for (int off = 32; off > 0; off >>= 1) {
        d0 += __shfl_xor(d0, off, 64);
        d1 += __shfl_xor(d1, off, 64);
        d2 += __shfl_xor(d2, off, 64);
        d3 += __shfl_xor(d3, off, 64);
    }
    if (lane == 0) {
        float4 r;
        r.x = __builtin_amdgcn_rcpf(d0);
        r.y = __builtin_amdgcn_rcpf(d1);
        r.z = __builtin_amdgcn_rcpf(d2);
        r.w = __builtin_amdgcn_rcpf(d3);
        *reinterpret_cast<float4*>(&rden[(size_t)n * 4]) = r;
    }
}

// ---- kernel 6 (stage 1, EDGE-major, no atomics): one wave per edge ----
// eout[e,d] = 0.25 * sum_{j in edge} sum_h a_h * ftT[n_j][d][h];  coef[i] written here
__global__ __launch_bounds__(256) void k_stage1(
        const int* __restrict__ ptrE, const int2* __restrict__ nodeOfE,
        const float* __restrict__ e_v, const float* __restrict__ rden,
        const float* __restrict__ e_e, const ushort4* __restrict__ ftbf,
        const float* __restrict__ invDE, const float* __restrict__ DV2,
        float* __restrict__ eout, float* __restrict__ coef) {
    int e = blockIdx.x * 4 + (threadIdx.x >> 6);
    int lane = threadIdx.x & 63;
    if (e >= E) return;
    int base = ptrE[e];
    int deg = ptrE[e + 1] - base;
    float4 ae = *reinterpret_cast<const float4*>(&e_e[(size_t)e * 4]);
    float qide = 0.25f * invDE[e];
    float acc = 0.f;
    #pragma unroll 2
    for (int j = 0; j < deg; ++j) {
        int2 ni = nodeOfE[base + j];
        int n = ni.x;
        float4 av = *reinterpret_cast<const float4*>(&e_v[(size_t)n * 4]);
        float4 rd = *reinterpret_cast<const float4*>(&rden[(size_t)n * 4]);
        ushort4 q = ftbf[(size_t)n * 64 + lane];
        float a0 = __expf(fmaxf(av.x + ae.x, 0.f)) * rd.x;
        float a1 = __expf(fmaxf(av.y + ae.y, 0.f)) * rd.y;
        float a2 = __expf(fmaxf(av.z + ae.z, 0.f)) * rd.z;
        float a3 = __expf(fmaxf(av.w + ae.w, 0.f)) * rd.w;
        acc += a0 * bf2f(q.x) + a1 * bf2f(q.y) + a2 * bf2f(q.z) + a3 * bf2f(q.w);
        if (lane == 0)
            coef[ni.y] = (a0 + a1 + a2 + a3) * qide * DV2[n];
    }
    eout[(size_t)e * 64 + lane] = acc * 0.25f;
}

// ---- kernel 7 (stage 2, NODE-major, no atomics): one wave per node ----
// vout[n,d] = sum_{j in node} coef[i_j] * eout[e_j, d]
__global__ __launch_bounds__(256) void k_stage2(
        const int* __restrict__ ptrN, const int2* __restrict__ edgeOfN,
        const float* __restrict__ coef,
        const float* __restrict__ eout, float* __restrict__ vout) {
    int n = blockIdx.x * 4 + (threadIdx.x >> 6);
    int lane = threadIdx.x & 63;
    if (n >= N) return;
    int base = ptrN[n];
    int deg = ptrN[n + 1] - base;
    float acc = 0.f;
    #pragma unroll 2
    for (int j = 0; j < deg; ++j) {
        int2 ei = edgeOfN[base + j];
        acc += coef[ei.y] * eout[(size_t)ei.x * 64 + lane];
    }
    vout[(size_t)n * 64 + lane] = acc;
}

extern "C" void kernel_launch(void* const* d_in, const int* in_sizes, int n_in,
                              void* d_out, int out_size, void* d_ws, size_t ws_size,
                              hipStream_t stream) {
    const float* vfeat   = (const float*)d_in[0];
    const float* efeat   = (const float*)d_in[1];
    const float* DV2     = (const float*)d_in[2];
    const float* invDE   = (const float*)d_in[3];
    const float* Wp      = (const float*)d_in[4];
    const float* Wv      = (const float*)d_in[5];
    const float* attn_v  = (const float*)d_in[6];
    const float* attn_e  = (const float*)d_in[7];
    const int* node_idx  = (const int*)d_in[8];
    const int* edge_idx  = (const int*)d_in[9];

    float* out  = (float*)d_out;
    float* vout = out;                       // [N][64]
    float* eout = out + (size_t)N * 64;      // [E][64]

    float* ws    = (float*)d_ws;
    float* uvT   = ws + OFF_UVT;
    float* ueT   = ws + OFF_UET;
    float* e_v   = ws + OFF_EV;
    float* e_e   = ws + OFF_EE;
    float* rden  = ws + OFF_RDEN;
    int*   cntN  = (int*)(ws + OFF_CNTN);
    int*   cntE  = (int*)(ws + OFF_CNTE);
    int*   ptrN  = (int*)(ws + OFF_PTRN);
    int*   ptrE  = (int*)(ws + OFF_PTRE);
    int2*  nodeOfE = (int2*)(ws + OFF_NOE2);
    int2*  edgeOfN = (int2*)(ws + OFF_EON2);
    float* coef  = ws + OFF_COEF;
    ushort4* ftbf = (ushort4*)(ws + OFF_FTBF);
    // reuse coef+ftbf region start for the fp32 ft staging? No: ft fp32 needs its own
    // space; place it after ftbf (N*64 ushort4 = N*128 float slots).
    float* ft    = ws + OFF_FTBF + (size_t)N * 128;   // [N][256] fp32 staging

    // zero the histogram counters (contiguous cntN+cntE)
    hipMemsetAsync(cntN, 0, (size_t)(N + E) * sizeof(int), stream);

    k_u<<<1, 256, 0, stream>>>(Wp, attn_v, attn_e, uvT, ueT);
    k_ev<<<(N + E + 3) / 4, 256, 0, stream>>>(vfeat, efeat, uvT, ueT, e_v, e_e);
    k_ft<<<dim3((N + 63) / 64, HD / 64), 256, 0, stream>>>(vfeat, Wv, DV2, ft);
    k_ftT<<<(N + 3) / 4, 256, 0, stream>>>(ft, ftbf);
    k_hist<<<(NNZ + 255) / 256, 256, 0, stream>>>(node_idx, edge_idx, cntN, cntE);
    k_scan<<<1, 1024, 0, stream>>>(cntN, ptrN, N);
    k_scan<<<1, 1024, 0, stream>>>(cntE, ptrE, E);
    k_scatter2<<<(NNZ + 255) / 256, 256, 0, stream>>>(node_idx, edge_idx,
                                                      cntN, cntE, edgeOfN, nodeOfE);
    k_den<<<(N + 3) / 4, 256, 0, stream>>>(ptrN, edgeOfN, e_v, e_e, rden);
    k_stage1<<<(E + 3) / 4, 256, 0, stream>>>(ptrE, nodeOfE, e_v, rden, e_e,
                                              ftbf, invDE, DV2, eout, coef);
    k_stage2<<<(N + 3) / 4, 256, 0, stream>>>(ptrN, edgeOfN, coef, eout, vout);
}

// Round 5
// 540.498 us; speedup vs baseline: 1.5497x; 1.2546x over previous
//
#include <hip/hip_runtime.h>
#include <math.h>

namespace {
constexpr int N = 50000;
constexpr int E = 20000;
constexpr int NNZ = 800000;
constexpr int DIN = 128;
constexpr int HD = 256;   // H*DOUT

// workspace layout (float-sized slots)
constexpr size_t OFF_UVT   = 0;                              // [4][128]
constexpr size_t OFF_UET   = 512;                            // [4][128]
constexpr size_t OFF_EV    = 1024;                           // [N][4]
constexpr size_t OFF_EE    = OFF_EV   + (size_t)N * 4;       // [E][4]
constexpr size_t OFF_RDEN  = OFF_EE   + (size_t)E * 4;       // [N][4]  (1/den)
constexpr size_t OFF_CNTN  = OFF_RDEN + (size_t)N * 4;       // int [N]
constexpr size_t OFF_CNTE  = OFF_CNTN + (size_t)N;           // int [E]
constexpr size_t OFF_PTRN  = OFF_CNTE + (size_t)E;           // int [N+1] (+pad)
constexpr size_t OFF_PTRE  = OFF_PTRN + (size_t)(N + 2);     // int [E+1] (+pad)
constexpr size_t OFF_FTBF  = (OFF_PTRE + (size_t)(E + 2) + 1) & ~(size_t)1; // ushort4 [N][64]
// overlay region: fp32 ft staging lives here first (N*256 slots), then is dead
// and the CSR/aw arrays reuse it (all written strictly after k_ftT consumed ft).
constexpr size_t OFF_OVER  = OFF_FTBF + (size_t)N * 128;
constexpr size_t OFF_FT    = OFF_OVER;                        // [N][256] fp32 staging
constexpr size_t OFF_EDGEOFN = OFF_OVER;                      // int [NNZ]
constexpr size_t OFF_NLISTN  = OFF_EDGEOFN + (size_t)NNZ;     // int [NNZ]
constexpr size_t OFF_NODEOFE = OFF_NLISTN  + (size_t)NNZ;     // int [NNZ]
constexpr size_t OFF_AWE     = (OFF_NODEOFE + (size_t)NNZ + 1) & ~(size_t)1; // ushort4 [NNZ]
constexpr size_t OFF_COEFN   = OFF_AWE + (size_t)NNZ * 2;     // float [NNZ]
constexpr size_t OFF_EOUTBF  = OFF_COEFN + (size_t)NNZ;       // ushort [E][64]

__device__ __forceinline__ unsigned short f2bf(float x) {
    unsigned int u = __float_as_uint(x);
    return (unsigned short)((u + 0x7FFFu + ((u >> 16) & 1u)) >> 16);
}
__device__ __forceinline__ float bf2f(unsigned short b) {
    return __uint_as_float(((unsigned int)b) << 16);
}
}

// ---- kernel 1: u tables: u[h][k] = sum_d W_p[k, h*64+d] * attn[h,d] ----
__global__ void k_u(const float* __restrict__ Wp, const float* __restrict__ attn_v,
                    const float* __restrict__ attn_e,
                    float* __restrict__ uvT, float* __restrict__ ueT) {
    int t = threadIdx.x;
    for (int task = t; task < 1024; task += 256) {
        int which = task >> 9;
        int hk = task & 511;
        int h = hk >> 7, k = hk & 127;
        const float* attn = which ? attn_e : attn_v;
        float s = 0.f;
        #pragma unroll 8
        for (int d = 0; d < 64; ++d)
            s += Wp[k * HD + h * 64 + d] * attn[h * 64 + d];
        (which ? ueT : uvT)[h * 128 + k] = s;
    }
}

// ---- kernel 2: e_v[n,h] = vfeat[n,:] . u_v[h,:];  e_e likewise (one wave/row)
__global__ void k_ev(const float* __restrict__ vfeat, const float* __restrict__ efeat,
                     const float* __restrict__ uvT, const float* __restrict__ ueT,
                     float* __restrict__ e_v, float* __restrict__ e_e) {
    __shared__ float su[2][4][128];
    int t = threadIdx.x;
    for (int idx = t; idx < 512; idx += 256) {
        su[0][0][idx] = uvT[idx];
        su[1][0][idx] = ueT[idx];
    }
    __syncthreads();
    int wave = t >> 6, lane = t & 63;
    int row = blockIdx.x * 4 + wave;
    if (row >= N + E) return;
    const float* feat; const float (*u)[128]; float* out; int r;
    if (row < N) { feat = vfeat; u = su[0]; out = e_v; r = row; }
    else         { feat = efeat; u = su[1]; out = e_e; r = row - N; }
    float f0 = feat[(size_t)r * DIN + lane];
    float f1 = feat[(size_t)r * DIN + 64 + lane];
    float p0 = f0 * u[0][lane] + f1 * u[0][64 + lane];
    float p1 = f0 * u[1][lane] + f1 * u[1][64 + lane];
    float p2 = f0 * u[2][lane] + f1 * u[2][64 + lane];
    float p3 = f0 * u[3][lane] + f1 * u[3][64 + lane];
    #pragma unroll
    for (int off = 32; off > 0; off >>= 1) {
        p0 += __shfl_xor(p0, off, 64);
        p1 += __shfl_xor(p1, off, 64);
        p2 += __shfl_xor(p2, off, 64);
        p3 += __shfl_xor(p3, off, 64);
    }
    if (lane == 0)
        *reinterpret_cast<float4*>(&out[(size_t)r * 4]) = make_float4(p0, p1, p2, p3);
}

// ---- kernel 3: ft = (vfeat @ W_v) * DV2, [N][256]; 64x64 tile SGEMM ----
__global__ __launch_bounds__(256) void k_ft(const float* __restrict__ vfeat,
                                            const float* __restrict__ Wv,
                                            const float* __restrict__ DV2,
                                            float* __restrict__ ft) {
    __shared__ float As[32][65];
    __shared__ float Bs[32][64];
    int tid = threadIdx.x;
    int rowBase = blockIdx.x * 64;
    int colBase = blockIdx.y * 64;
    int tx = tid & 15, ty = tid >> 4;
    int tx4 = tx * 4, ty4 = ty * 4;
    float acc[4][4] = {};
    for (int k0 = 0; k0 < DIN; k0 += 32) {
        #pragma unroll
        for (int i = 0; i < 2; ++i) {
            int e = tid + i * 256;
            int r = e >> 3;
            int k4 = e & 7;
            int row = rowBase + r;
            float4 v = make_float4(0.f, 0.f, 0.f, 0.f);
            if (row < N)
                v = *reinterpret_cast<const float4*>(&vfeat[(size_t)row * DIN + k0 + k4 * 4]);
            As[k4 * 4 + 0][r] = v.x;
            As[k4 * 4 + 1][r] = v.y;
            As[k4 * 4 + 2][r] = v.z;
            As[k4 * 4 + 3][r] = v.w;
        }
        #pragma unroll
        for (int i = 0; i < 2; ++i) {
            int e = tid + i * 256;
            int k = e >> 4;
            int c4 = e & 15;
            *reinterpret_cast<float4*>(&Bs[k][c4 * 4]) =
                *reinterpret_cast<const float4*>(&Wv[(size_t)(k0 + k) * HD + colBase + c4 * 4]);
        }
        __syncthreads();
        #pragma unroll 8
        for (int k = 0; k < 32; ++k) {
            float a0 = As[k][ty4 + 0], a1 = As[k][ty4 + 1];
            float a2 = As[k][ty4 + 2], a3 = As[k][ty4 + 3];
            float4 b = *reinterpret_cast<const float4*>(&Bs[k][tx4]);
            acc[0][0] += a0 * b.x; acc[0][1] += a0 * b.y; acc[0][2] += a0 * b.z; acc[0][3] += a0 * b.w;
            acc[1][0] += a1 * b.x; acc[1][1] += a1 * b.y; acc[1][2] += a1 * b.z; acc[1][3] += a1 * b.w;
            acc[2][0] += a2 * b.x; acc[2][1] += a2 * b.y; acc[2][2] += a2 * b.z; acc[2][3] += a2 * b.w;
            acc[3][0] += a3 * b.x; acc[3][1] += a3 * b.y; acc[3][2] += a3 * b.z; acc[3][3] += a3 * b.w;
        }
        __syncthreads();
    }
    #pragma unroll
    for (int mi = 0; mi < 4; ++mi) {
        int row = rowBase + ty4 + mi;
        if (row < N) {
            float dv = DV2[row];
            float4 o = make_float4(acc[mi][0] * dv, acc[mi][1] * dv,
                                   acc[mi][2] * dv, acc[mi][3] * dv);
            *reinterpret_cast<float4*>(&ft[(size_t)row * HD + colBase + tx4]) = o;
        }
    }
}

// ---- kernel 3b: ft[n][h*64+d] -> packed bf16 ftbf[n][d] = {h0,h1,h2,h3} ----
__global__ void k_ftT(const float* __restrict__ ft, ushort4* __restrict__ ftbf) {
    int n = blockIdx.x * 4 + (threadIdx.x >> 6);
    int lane = threadIdx.x & 63;
    if (n >= N) return;
    const float* row = &ft[(size_t)n * HD];
    ushort4 q;
    q.x = f2bf(row[lane]);
    q.y = f2bf(row[64 + lane]);
    q.z = f2bf(row[128 + lane]);
    q.w = f2bf(row[192 + lane]);
    ftbf[(size_t)n * 64 + lane] = q;
}

// ---- kernel 4: int histograms only ----
__global__ void k_hist(const int* __restrict__ node_idx, const int* __restrict__ edge_idx,
                       int* __restrict__ cntN, int* __restrict__ cntE) {
    int i = blockIdx.x * 256 + threadIdx.x;
    if (i >= NNZ) return;
    atomicAdd(&cntN[node_idx[i]], 1);
    atomicAdd(&cntE[edge_idx[i]], 1);
}

// ---- scan: single block; cnt becomes the scatter cursor (= exclusive prefix) ----
__global__ __launch_bounds__(1024) void k_scan(int* __restrict__ cnt,
                                               int* __restrict__ ptr, int count) {
    __shared__ int part[1024];
    int t = threadIdx.x;
    int C = (count + 1023) / 1024;
    int lo = t * C, hi = min(lo + C, count);
    int s = 0;
    for (int i = lo; i < hi; ++i) s += cnt[i];
    part[t] = s;
    __syncthreads();
    for (int off = 1; off < 1024; off <<= 1) {
        int v = part[t];
        int add = (t >= off) ? part[t - off] : 0;
        __syncthreads();
        part[t] = v + add;
        __syncthreads();
    }
    int run = (t == 0) ? 0 : part[t - 1];
    for (int i = lo; i < hi; ++i) {
        int cv = cnt[i];
        ptr[i] = run;
        cnt[i] = run;
        run += cv;
    }
    if (t == 0) ptr[count] = part[1023];
}

// ---- node-CSR scatter: edgeOfN[pos]=e, nListN[pos]=n ----
__global__ void k_scatterN(const int* __restrict__ node_idx, const int* __restrict__ edge_idx,
                           int* __restrict__ cursorN,
                           int* __restrict__ edgeOfN, int* __restrict__ nListN) {
    int i = blockIdx.x * 256 + threadIdx.x;
    if (i >= NNZ) return;
    int n = node_idx[i], e = edge_idx[i];
    int pos = atomicAdd(&cursorN[n], 1);
    edgeOfN[pos] = e;
    nListN[pos] = n;
}

// ---- rden[n] = 1 / sum_{e in n} exp(relu(e_v[n]+e_e[e])), node-major ----
__global__ __launch_bounds__(256) void k_den(
        const int* __restrict__ ptrN, const int* __restrict__ edgeOfN,
        const float* __restrict__ e_v, const float* __restrict__ e_e,
        float* __restrict__ rden) {
    int n = blockIdx.x * 4 + (threadIdx.x >> 6);
    int lane = threadIdx.x & 63;
    if (n >= N) return;
    int base = ptrN[n];
    int deg = ptrN[n + 1] - base;
    float4 av = *reinterpret_cast<const float4*>(&e_v[(size_t)n * 4]);
    float d0 = 0.f, d1 = 0.f, d2 = 0.f, d3 = 0.f;
    for (int j = lane; j < deg; j += 64) {
        int e = edgeOfN[base + j];
        float4 ae = *reinterpret_cast<const float4*>(&e_e[(size_t)e * 4]);
        d0 += __expf(fmaxf(av.x + ae.x, 0.f));
        d1 += __expf(fmaxf(av.y + ae.y, 0.f));
        d2 += __expf(fmaxf(av.z + ae.z, 0.f));
        d3 += __expf(fmaxf(av.w + ae.w, 0.f));
    }
    #pragma unroll
    for (int off = 32; off > 0; off >>= 1) {
        d0 += __shfl_xor(d0, off, 64);
        d1 += __shfl_xor(d1, off, 64);
        d2 += __shfl_xor(d2, off, 64);
        d3 += __shfl_xor(d3, off, 64);
    }
    if (lane == 0) {
        float4 r;
        r.x = __builtin_amdgcn_rcpf(d0);
        r.y = __builtin_amdgcn_rcpf(d1);
        r.z = __builtin_amdgcn_rcpf(d2);
        r.w = __builtin_amdgcn_rcpf(d3);
        *reinterpret_cast<float4*>(&rden[(size_t)n * 4]) = r;
    }
}

// ---- edge-CSR scatter fused with attention-weight precompute ----
// processes node-CSR order -> nodeOfE approx node-sorted within each edge.
// awE[posE] = packed bf16 {a0,a1,a2,a3} aligned with nodeOfE;
// coefN[pos] = 0.25*(sum a)*invDE[e]*DV2[n] aligned with edgeOfN (node-CSR).
__global__ void k_scatterE_aw(const int* __restrict__ edgeOfN, const int* __restrict__ nListN,
                              int* __restrict__ cursorE,
                              const float* __restrict__ e_v, const float* __restrict__ e_e,
                              const float* __restrict__ rden,
                              const float* __restrict__ invDE, const float* __restrict__ DV2,
                              int* __restrict__ nodeOfE, ushort4* __restrict__ awE,
                              float* __restrict__ coefN) {
    int pos = blockIdx.x * 256 + threadIdx.x;
    if (pos >= NNZ) return;
    int e = edgeOfN[pos];
    int n = nListN[pos];
    float4 av = *reinterpret_cast<const float4*>(&e_v[(size_t)n * 4]);
    float4 ae = *reinterpret_cast<const float4*>(&e_e[(size_t)e * 4]);
    float4 rd = *reinterpret_cast<const float4*>(&rden[(size_t)n * 4]);
    float a0 = __expf(fmaxf(av.x + ae.x, 0.f)) * rd.x;
    float a1 = __expf(fmaxf(av.y + ae.y, 0.f)) * rd.y;
    float a2 = __expf(fmaxf(av.z + ae.z, 0.f)) * rd.z;
    float a3 = __expf(fmaxf(av.w + ae.w, 0.f)) * rd.w;
    int posE = atomicAdd(&cursorE[e], 1);
    nodeOfE[posE] = n;
    ushort4 w;
    w.x = f2bf(a0); w.y = f2bf(a1); w.z = f2bf(a2); w.w = f2bf(a3);
    awE[posE] = w;
    coefN[pos] = 0.25f * (a0 + a1 + a2 + a3) * invDE[e] * DV2[n];
}

// ---- stage 1 (EDGE-major, no atomics): one wave per edge ----
// eout[e,d] = 0.25 * sum_j sum_h aw[j,h] * ftbf[n_j][d][h]
__global__ __launch_bounds__(256) void k_stage1(
        const int* __restrict__ ptrE, const int* __restrict__ nodeOfE,
        const ushort4* __restrict__ awE, const ushort4* __restrict__ ftbf,
        float* __restrict__ eout, unsigned short* __restrict__ eoutbf) {
    int e = blockIdx.x * 4 + (threadIdx.x >> 6);
    int lane = threadIdx.x & 63;
    if (e >= E) return;
    int base = ptrE[e];
    int deg = ptrE[e + 1] - base;
    float acc = 0.f;
    #pragma unroll 4
    for (int j = 0; j < deg; ++j) {
        int n = nodeOfE[base + j];
        ushort4 aw = awE[base + j];
        ushort4 q = ftbf[(size_t)n * 64 + lane];
        acc += bf2f(aw.x) * bf2f(q.x) + bf2f(aw.y) * bf2f(q.y)
             + bf2f(aw.z) * bf2f(q.z) + bf2f(aw.w) * bf2f(q.w);
    }
    float o = acc * 0.25f;
    eout[(size_t)e * 64 + lane] = o;
    eoutbf[(size_t)e * 64 + lane] = f2bf(o);
}

// ---- stage 2 (NODE-major, no atomics): one wave per node ----
// vout[n,d] = sum_j coefN[base+j] * eoutbf[e_j, d]
__global__ __launch_bounds__(256) void k_stage2(
        const int* __restrict__ ptrN, const int* __restrict__ edgeOfN,
        const float* __restrict__ coefN,
        const unsigned short* __restrict__ eoutbf, float* __restrict__ vout) {
    int n = blockIdx.x * 4 + (threadIdx.x >> 6);
    int lane = threadIdx.x & 63;
    if (n >= N) return;
    int base = ptrN[n];
    int deg = ptrN[n + 1] - base;
    float acc = 0.f;
    #pragma unroll 4
    for (int j = 0; j < deg; ++j) {
        int e = edgeOfN[base + j];
        float cf = coefN[base + j];
        acc += cf * bf2f(eoutbf[(size_t)e * 64 + lane]);
    }
    vout[(size_t)n * 64 + lane] = acc;
}

extern "C" void kernel_launch(void* const* d_in, const int* in_sizes, int n_in,
                              void* d_out, int out_size, void* d_ws, size_t ws_size,
                              hipStream_t stream) {
    const float* vfeat   = (const float*)d_in[0];
    const float* efeat   = (const float*)d_in[1];
    const float* DV2     = (const float*)d_in[2];
    const float* invDE   = (const float*)d_in[3];
    const float* Wp      = (const float*)d_in[4];
    const float* Wv      = (const float*)d_in[5];
    const float* attn_v  = (const float*)d_in[6];
    const float* attn_e  = (const float*)d_in[7];
    const int* node_idx  = (const int*)d_in[8];
    const int* edge_idx  = (const int*)d_in[9];

    float* out  = (float*)d_out;
    float* vout = out;                       // [N][64]
    float* eout = out + (size_t)N * 64;      // [E][64]

    float* ws    = (float*)d_ws;
    float* uvT   = ws + OFF_UVT;
    float* ueT   = ws + OFF_UET;
    float* e_v   = ws + OFF_EV;
    float* e_e   = ws + OFF_EE;
    float* rden  = ws + OFF_RDEN;
    int*   cntN  = (int*)(ws + OFF_CNTN);
    int*   cntE  = (int*)(ws + OFF_CNTE);
    int*   ptrN  = (int*)(ws + OFF_PTRN);
    int*   ptrE  = (int*)(ws + OFF_PTRE);
    ushort4* ftbf = (ushort4*)(ws + OFF_FTBF);
    float* ft    = ws + OFF_FT;              // fp32 staging (overlaid, dead after k_ftT)
    int*   edgeOfN = (int*)(ws + OFF_EDGEOFN);
    int*   nListN  = (int*)(ws + OFF_NLISTN);
    int*   nodeOfE = (int*)(ws + OFF_NODEOFE);
    ushort4* awE  = (ushort4*)(ws + OFF_AWE);
    float* coefN = ws + OFF_COEFN;
    unsigned short* eoutbf = (unsigned short*)(ws + OFF_EOUTBF);

    // zero the histogram counters (contiguous cntN+cntE)
    hipMemsetAsync(cntN, 0, (size_t)(N + E) * sizeof(int), stream);

    k_u<<<1, 256, 0, stream>>>(Wp, attn_v, attn_e, uvT, ueT);
    k_ev<<<(N + E + 3) / 4, 256, 0, stream>>>(vfeat, efeat, uvT, ueT, e_v, e_e);
    k_ft<<<dim3((N + 63) / 64, HD / 64), 256, 0, stream>>>(vfeat, Wv, DV2, ft);
    k_ftT<<<(N + 3) / 4, 256, 0, stream>>>(ft, ftbf);
    // --- ft (fp32) is dead from here; overlay region reused for CSR arrays ---
    k_hist<<<(NNZ + 255) / 256, 256, 0, stream>>>(node_idx, edge_idx, cntN, cntE);
    k_scan<<<1, 1024, 0, stream>>>(cntN, ptrN, N);
    k_scan<<<1, 1024, 0, stream>>>(cntE, ptrE, E);
    k_scatterN<<<(NNZ + 255) / 256, 256, 0, stream>>>(node_idx, edge_idx,
                                                      cntN, edgeOfN, nListN);
    k_den<<<(N + 3) / 4, 256, 0, stream>>>(ptrN, edgeOfN, e_v, e_e, rden);
    k_scatterE_aw<<<(NNZ + 255) / 256, 256, 0, stream>>>(edgeOfN, nListN, cntE,
                                                         e_v, e_e, rden, invDE, DV2,
                                                         nodeOfE, awE, coefN);
    k_stage1<<<(E + 3) / 4, 256, 0, stream>>>(ptrE, nodeOfE, awE, ftbf, eout, eoutbf);
    k_stage2<<<(N + 3) / 4, 256, 0, stream>>>(ptrN, edgeOfN, coefN, eoutbf, vout);
}